// Round 1
// baseline (1718.953 us; speedup 1.0000x reference)
//
#include <hip/hip_runtime.h>
#include <math.h>

#define N_NODES 40000
#define N_EDGES 640000
#define D 128
#define H 8
#define C 16

// ws layout (float offsets):
//  x      : 0         .. 5,120,000   (N*128)
//  al     : 5,120,000 .. 5,440,000   (N*8)
//  ar     : 5,440,000 .. 5,760,000   (N*8)
//  lg/ex  : 5,760,000 .. 10,880,000  (E*8)
//  mx(u32): 10,880,000.. 11,200,000  (N*8)
//  sm     : 11,200,000.. 11,520,000  (N*8)
//  agg    : 11,520,000.. 16,640,000  (N*128)
// total 16,640,000 floats = 66.56 MB

__device__ __forceinline__ unsigned f2ord(float f) {
  unsigned u = __float_as_uint(f);
  return (u & 0x80000000u) ? ~u : (u | 0x80000000u);
}
__device__ __forceinline__ float ord2f(unsigned u) {
  return (u & 0x80000000u) ? __uint_as_float(u ^ 0x80000000u)
                           : __uint_as_float(~u);
}

// Fused: x = feat@Wlin ; res = feat@Wres -> d_out ; alpha_l/r head reductions.
// 64 rows/block, 256 threads = 256 output columns (128 lin + 128 res).
__global__ __launch_bounds__(256) void k_fused_gemm(
    const float* __restrict__ feat, const float* __restrict__ Wlin,
    const float* __restrict__ Wres, const float* __restrict__ attl,
    const float* __restrict__ attr, float* __restrict__ x,
    float* __restrict__ al, float* __restrict__ ar, float* __restrict__ outp)
{
  __shared__ float sf[64 * 128];
  const int t = threadIdx.x;
  const long rowbase = (long)blockIdx.x * 64;

  // stage 64x128 feature tile (contiguous 32KB) via float4
  const float4* fg = (const float4*)(feat + rowbase * 128);
  float4* sf4 = (float4*)sf;
  #pragma unroll
  for (int i = 0; i < 8; ++i) sf4[t + i * 256] = fg[t + i * 256];
  __syncthreads();

  float acc[64];
  #pragma unroll
  for (int r = 0; r < 64; ++r) acc[r] = 0.f;

  const float* W = (t < 128) ? (Wlin + t) : (Wres + (t - 128));
  for (int k = 0; k < 128; k += 4) {
    const float w0 = W[(k + 0) * 128];
    const float w1 = W[(k + 1) * 128];
    const float w2 = W[(k + 2) * 128];
    const float w3 = W[(k + 3) * 128];
    #pragma unroll
    for (int r = 0; r < 64; ++r) {
      const float4 f = *(const float4*)&sf[r * 128 + k];
      acc[r] = fmaf(f.w, w3, fmaf(f.z, w2, fmaf(f.y, w1, fmaf(f.x, w0, acc[r]))));
    }
  }
  __syncthreads();

  if (t < 128) {
    #pragma unroll
    for (int r = 0; r < 64; ++r) {
      x[(rowbase + r) * 128 + t] = acc[r];
      sf[r * 128 + t] = acc[r];   // reuse LDS as x tile for alpha epilogue
    }
  } else {
    #pragma unroll
    for (int r = 0; r < 64; ++r)
      outp[(rowbase + r) * 128 + (t - 128)] = acc[r];
  }
  __syncthreads();

  // alpha: 64 rows x 8 heads = 512 tasks over 256 threads
  #pragma unroll
  for (int i = 0; i < 2; ++i) {
    const int task = t + i * 256;
    const int r = task >> 3, h = task & 7;
    float sl = 0.f, sr = 0.f;
    #pragma unroll
    for (int c = 0; c < 16; ++c) {
      const float xv = sf[r * 128 + h * 16 + c];
      sl = fmaf(xv, attl[h * 16 + c], sl);
      sr = fmaf(xv, attr[h * 16 + c], sr);
    }
    al[(rowbase + r) * 8 + h] = sl;
    ar[(rowbase + r) * 8 + h] = sr;
  }
}

__global__ __launch_bounds__(256) void k_logit_max(
    const int* __restrict__ src, const int* __restrict__ dst,
    const float* __restrict__ ew, const float* __restrict__ al,
    const float* __restrict__ ar, float* __restrict__ lg,
    unsigned* __restrict__ mx)
{
  const int e = blockIdx.x * 256 + threadIdx.x;
  if (e >= N_EDGES) return;
  const int s = src[e], d = dst[e];
  const float w = ew[e];
  const float4 l0 = *(const float4*)&al[(long)s * 8];
  const float4 l1 = *(const float4*)&al[(long)s * 8 + 4];
  const float4 r0 = *(const float4*)&ar[(long)d * 8];
  const float4 r1 = *(const float4*)&ar[(long)d * 8 + 4];
  float lv[8] = {l0.x + r0.x, l0.y + r0.y, l0.z + r0.z, l0.w + r0.w,
                 l1.x + r1.x, l1.y + r1.y, l1.z + r1.z, l1.w + r1.w};
  #pragma unroll
  for (int h = 0; h < 8; ++h) {
    float a = w * lv[h];
    a = (a >= 0.f) ? a : 0.2f * a;   // leaky_relu(0.2), matches reference
    lv[h] = a;
    atomicMax(&mx[(long)d * 8 + h], f2ord(a));
  }
  float4* out = (float4*)&lg[(long)e * 8];
  out[0] = make_float4(lv[0], lv[1], lv[2], lv[3]);
  out[1] = make_float4(lv[4], lv[5], lv[6], lv[7]);
}

__global__ __launch_bounds__(256) void k_exp_sum(
    const int* __restrict__ dst, float* __restrict__ lg,
    const unsigned* __restrict__ mx, float* __restrict__ sm)
{
  const int e = blockIdx.x * 256 + threadIdx.x;
  if (e >= N_EDGES) return;
  const int d = dst[e];
  float4 v0 = *(float4*)&lg[(long)e * 8];
  float4 v1 = *(float4*)&lg[(long)e * 8 + 4];
  float ex[8];
  ex[0] = expf(v0.x - ord2f(mx[(long)d * 8 + 0]));
  ex[1] = expf(v0.y - ord2f(mx[(long)d * 8 + 1]));
  ex[2] = expf(v0.z - ord2f(mx[(long)d * 8 + 2]));
  ex[3] = expf(v0.w - ord2f(mx[(long)d * 8 + 3]));
  ex[4] = expf(v1.x - ord2f(mx[(long)d * 8 + 4]));
  ex[5] = expf(v1.y - ord2f(mx[(long)d * 8 + 5]));
  ex[6] = expf(v1.z - ord2f(mx[(long)d * 8 + 6]));
  ex[7] = expf(v1.w - ord2f(mx[(long)d * 8 + 7]));
  #pragma unroll
  for (int h = 0; h < 8; ++h) atomicAdd(&sm[(long)d * 8 + h], ex[h]);
  float4* out = (float4*)&lg[(long)e * 8];
  out[0] = make_float4(ex[0], ex[1], ex[2], ex[3]);
  out[1] = make_float4(ex[4], ex[5], ex[6], ex[7]);
}

// 32 lanes per edge: lane j handles channels 4j..4j+3 (head j/4)
__global__ __launch_bounds__(256) void k_scatter(
    const int* __restrict__ src, const int* __restrict__ dst,
    const float* __restrict__ lg, const float* __restrict__ sm,
    const float* __restrict__ x, float* __restrict__ agg)
{
  const int gid = blockIdx.x * 256 + threadIdx.x;
  const int e = gid >> 5;
  const int j = gid & 31;
  if (e >= N_EDGES) return;
  const int s = src[e], d = dst[e];
  const int h = j >> 2;
  const float coef = lg[(long)e * 8 + h] / sm[(long)d * 8 + h];
  const float4 xv = *(const float4*)&x[(long)s * 128 + j * 4];
  float* a = &agg[(long)d * 128 + j * 4];
  atomicAdd(a + 0, xv.x * coef);
  atomicAdd(a + 1, xv.y * coef);
  atomicAdd(a + 2, xv.z * coef);
  atomicAdd(a + 3, xv.w * coef);
}

__global__ __launch_bounds__(256) void k_final(
    const float* __restrict__ agg, float* __restrict__ outp)
{
  const int i = blockIdx.x * 256 + threadIdx.x;  // float4 index, N*128/4 total
  const float4 a = ((const float4*)agg)[i];
  float4 o = ((float4*)outp)[i];
  o.x += (a.x > 0.f) ? a.x : expm1f(a.x);
  o.y += (a.y > 0.f) ? a.y : expm1f(a.y);
  o.z += (a.z > 0.f) ? a.z : expm1f(a.z);
  o.w += (a.w > 0.f) ? a.w : expm1f(a.w);
  ((float4*)outp)[i] = o;
}

extern "C" void kernel_launch(void* const* d_in, const int* in_sizes, int n_in,
                              void* d_out, int out_size, void* d_ws, size_t ws_size,
                              hipStream_t stream) {
  const float* feat = (const float*)d_in[0];
  const int*   eidx = (const int*)d_in[1];
  const float* ew   = (const float*)d_in[2];
  const float* Wlin = (const float*)d_in[3];
  const float* attl = (const float*)d_in[4];
  const float* attr = (const float*)d_in[5];
  const float* Wres = (const float*)d_in[6];
  float* outp = (float*)d_out;

  float* ws = (float*)d_ws;
  float*    x   = ws;
  float*    al  = ws + 5120000;
  float*    ar  = ws + 5440000;
  float*    lg  = ws + 5760000;
  unsigned* mx  = (unsigned*)(ws + 10880000);
  float*    sm  = ws + 11200000;
  float*    agg = ws + 11520000;

  const int* src = eidx;
  const int* dst = eidx + N_EDGES;

  hipMemsetAsync(mx,  0, (size_t)N_NODES * H * 4, stream);
  hipMemsetAsync(sm,  0, (size_t)N_NODES * H * 4, stream);
  hipMemsetAsync(agg, 0, (size_t)N_NODES * D * 4, stream);

  k_fused_gemm<<<N_NODES / 64, 256, 0, stream>>>(feat, Wlin, Wres, attl, attr,
                                                 x, al, ar, outp);
  k_logit_max<<<(N_EDGES + 255) / 256, 256, 0, stream>>>(src, dst, ew, al, ar, lg, mx);
  k_exp_sum<<<(N_EDGES + 255) / 256, 256, 0, stream>>>(dst, lg, mx, sm);
  k_scatter<<<(N_EDGES * 32) / 256, 256, 0, stream>>>(src, dst, lg, sm, x, agg);
  k_final<<<(N_NODES * D / 4) / 256, 256, 0, stream>>>(agg, outp);
}

// Round 2
// 393.766 us; speedup vs baseline: 4.3654x; 4.3654x over previous
//
#include <hip/hip_runtime.h>
#include <math.h>

#define N_NODES 40000
#define N_EDGES 640000
#define D 128
#define H 8
#define C 16

// ws layout (float offsets):
//  x    : 0          .. 5,120,000   (N*128)
//  al   : 5,120,000  .. 5,440,000   (N*8)
//  ar   : 5,440,000  .. 5,760,000   (N*8)
//  plg  : 5,760,000  .. 10,880,000  (E*8, dst-sorted logits)
//  psrc : 10,880,000 .. 11,520,000  (E ints, dst-sorted src ids)
//  row  : 11,520,000 .. 11,560,001  (N+1 ints, CSR offsets)
//  cur  : 11,600,000 .. 11,640,000  (N ints, fill cursors)
//  cnt  : 11,700,000 .. 11,740,000  (N ints, histogram)

// Fused: x = feat@Wlin ; res = feat@Wres -> d_out ; alpha_l/r head reductions.
__global__ __launch_bounds__(256) void k_fused_gemm(
    const float* __restrict__ feat, const float* __restrict__ Wlin,
    const float* __restrict__ Wres, const float* __restrict__ attl,
    const float* __restrict__ attr, float* __restrict__ x,
    float* __restrict__ al, float* __restrict__ ar, float* __restrict__ outp)
{
  __shared__ float sf[64 * 128];
  const int t = threadIdx.x;
  const long rowbase = (long)blockIdx.x * 64;

  const float4* fg = (const float4*)(feat + rowbase * 128);
  float4* sf4 = (float4*)sf;
  #pragma unroll
  for (int i = 0; i < 8; ++i) sf4[t + i * 256] = fg[t + i * 256];
  __syncthreads();

  float acc[64];
  #pragma unroll
  for (int r = 0; r < 64; ++r) acc[r] = 0.f;

  const float* W = (t < 128) ? (Wlin + t) : (Wres + (t - 128));
  for (int k = 0; k < 128; k += 4) {
    const float w0 = W[(k + 0) * 128];
    const float w1 = W[(k + 1) * 128];
    const float w2 = W[(k + 2) * 128];
    const float w3 = W[(k + 3) * 128];
    #pragma unroll
    for (int r = 0; r < 64; ++r) {
      const float4 f = *(const float4*)&sf[r * 128 + k];
      acc[r] = fmaf(f.w, w3, fmaf(f.z, w2, fmaf(f.y, w1, fmaf(f.x, w0, acc[r]))));
    }
  }
  __syncthreads();

  if (t < 128) {
    #pragma unroll
    for (int r = 0; r < 64; ++r) {
      x[(rowbase + r) * 128 + t] = acc[r];
      sf[r * 128 + t] = acc[r];
    }
  } else {
    #pragma unroll
    for (int r = 0; r < 64; ++r)
      outp[(rowbase + r) * 128 + (t - 128)] = acc[r];
  }
  __syncthreads();

  #pragma unroll
  for (int i = 0; i < 2; ++i) {
    const int task = t + i * 256;
    const int r = task >> 3, h = task & 7;
    float sl = 0.f, sr = 0.f;
    #pragma unroll
    for (int c = 0; c < 16; ++c) {
      const float xv = sf[r * 128 + h * 16 + c];
      sl = fmaf(xv, attl[h * 16 + c], sl);
      sr = fmaf(xv, attr[h * 16 + c], sr);
    }
    al[(rowbase + r) * 8 + h] = sl;
    ar[(rowbase + r) * 8 + h] = sr;
  }
}

__global__ __launch_bounds__(256) void k_hist(
    const int* __restrict__ dst, int* __restrict__ cnt)
{
  const int e = blockIdx.x * 256 + threadIdx.x;
  if (e >= N_EDGES) return;
  atomicAdd(&cnt[dst[e]], 1);
}

// Single-block exclusive scan over cnt[N] -> row[N+1], copy to cur[N].
__global__ __launch_bounds__(256) void k_scan(
    const int* __restrict__ cnt, int* __restrict__ row, int* __restrict__ cur)
{
  __shared__ int part[256];
  const int t = threadIdx.x;
  const int CH = (N_NODES + 255) / 256;  // 157
  const int base = t * CH;
  const int end = min(base + CH, N_NODES);
  int local = 0;
  for (int i = base; i < end; ++i) local += cnt[i];
  part[t] = local;
  __syncthreads();
  if (t == 0) {
    int run = 0;
    for (int i = 0; i < 256; ++i) { int tmp = part[i]; part[i] = run; run += tmp; }
  }
  __syncthreads();
  int run = part[t];
  for (int i = base; i < end; ++i) {
    row[i] = run; cur[i] = run;
    run += cnt[i];
  }
  if (t == 0) row[N_NODES] = N_EDGES;
}

// Compute per-edge logits (leaky-relu'd) and scatter into dst-sorted order.
__global__ __launch_bounds__(256) void k_fill_logit(
    const int* __restrict__ src, const int* __restrict__ dst,
    const float* __restrict__ ew, const float* __restrict__ al,
    const float* __restrict__ ar, int* __restrict__ cur,
    float* __restrict__ plg, int* __restrict__ psrc)
{
  const int e = blockIdx.x * 256 + threadIdx.x;
  if (e >= N_EDGES) return;
  const int s = src[e], d = dst[e];
  const float w = ew[e];
  const float4 l0 = *(const float4*)&al[(long)s * 8];
  const float4 l1 = *(const float4*)&al[(long)s * 8 + 4];
  const float4 r0 = *(const float4*)&ar[(long)d * 8];
  const float4 r1 = *(const float4*)&ar[(long)d * 8 + 4];
  float lv[8] = {l0.x + r0.x, l0.y + r0.y, l0.z + r0.z, l0.w + r0.w,
                 l1.x + r1.x, l1.y + r1.y, l1.z + r1.z, l1.w + r1.w};
  #pragma unroll
  for (int h = 0; h < 8; ++h) {
    float a = w * lv[h];
    lv[h] = (a >= 0.f) ? a : 0.2f * a;   // leaky_relu(0.2)
  }
  const int p = atomicAdd(&cur[d], 1);
  psrc[p] = s;
  float4* o = (float4*)&plg[(long)p * 8];
  o[0] = make_float4(lv[0], lv[1], lv[2], lv[3]);
  o[1] = make_float4(lv[4], lv[5], lv[6], lv[7]);
}

// One wave per node: softmax (max+sum via xor-shuffles) + weighted gather
// of x[src] + elu + residual. Lane owns channels [2*lane, 2*lane+1],
// head = lane>>3. Zero atomics.
__global__ __launch_bounds__(256) void k_node_agg(
    const int* __restrict__ row, const int* __restrict__ psrc,
    const float* __restrict__ plg, const float* __restrict__ x,
    float* __restrict__ outp)
{
  const int wave = threadIdx.x >> 6;
  const int lane = threadIdx.x & 63;
  const int d = blockIdx.x * 4 + wave;
  const int start = row[d], end = row[d + 1];
  const int deg = end - start;
  if (deg <= 0) return;  // out already holds residual; elu(0)=0

  const float* base = plg + (long)start * 8;
  const int nv = deg * 8;

  // per-head max: lane l covers values v = l, l+64, ... ; head(v) = v&7 = l&7
  float m = -INFINITY;
  for (int v = lane; v < nv; v += 64) m = fmaxf(m, base[v]);
  m = fmaxf(m, __shfl_xor(m, 8));
  m = fmaxf(m, __shfl_xor(m, 16));
  m = fmaxf(m, __shfl_xor(m, 32));   // m = max for head (lane&7)

  float ssum = 0.f;
  for (int v = lane; v < nv; v += 64) ssum += __expf(base[v] - m);
  ssum += __shfl_xor(ssum, 8);
  ssum += __shfl_xor(ssum, 16);
  ssum += __shfl_xor(ssum, 32);      // ssum = denom for head (lane&7)

  const int h = lane >> 3;           // my channel pair's head
  const float mh = __shfl(m, h);     // lane h holds head h's stats
  const float rs = 1.0f / __shfl(ssum, h);

  float2 acc = make_float2(0.f, 0.f);
  for (int i = 0; i < deg; ++i) {
    const long p = start + i;
    const float coef = __expf(plg[p * 8 + h] - mh) * rs;
    const int s = psrc[p];
    const float2 xv = *(const float2*)&x[(long)s * 128 + lane * 2];
    acc.x = fmaf(xv.x, coef, acc.x);
    acc.y = fmaf(xv.y, coef, acc.y);
  }

  float2 o = *(float2*)&outp[(long)d * 128 + lane * 2];
  o.x += (acc.x > 0.f) ? acc.x : expm1f(acc.x);
  o.y += (acc.y > 0.f) ? acc.y : expm1f(acc.y);
  *(float2*)&outp[(long)d * 128 + lane * 2] = o;
}

extern "C" void kernel_launch(void* const* d_in, const int* in_sizes, int n_in,
                              void* d_out, int out_size, void* d_ws, size_t ws_size,
                              hipStream_t stream) {
  const float* feat = (const float*)d_in[0];
  const int*   eidx = (const int*)d_in[1];
  const float* ew   = (const float*)d_in[2];
  const float* Wlin = (const float*)d_in[3];
  const float* attl = (const float*)d_in[4];
  const float* attr = (const float*)d_in[5];
  const float* Wres = (const float*)d_in[6];
  float* outp = (float*)d_out;

  float* ws = (float*)d_ws;
  float* x    = ws;
  float* al   = ws + 5120000;
  float* ar   = ws + 5440000;
  float* plg  = ws + 5760000;
  int*   psrc = (int*)(ws + 10880000);
  int*   row  = (int*)(ws + 11520000);
  int*   cur  = (int*)(ws + 11600000);
  int*   cnt  = (int*)(ws + 11700000);

  const int* src = eidx;
  const int* dst = eidx + N_EDGES;

  hipMemsetAsync(cnt, 0, (size_t)N_NODES * 4, stream);

  k_fused_gemm<<<N_NODES / 64, 256, 0, stream>>>(feat, Wlin, Wres, attl, attr,
                                                 x, al, ar, outp);
  k_hist<<<(N_EDGES + 255) / 256, 256, 0, stream>>>(dst, cnt);
  k_scan<<<1, 256, 0, stream>>>(cnt, row, cur);
  k_fill_logit<<<(N_EDGES + 255) / 256, 256, 0, stream>>>(src, dst, ew, al, ar,
                                                          cur, plg, psrc);
  k_node_agg<<<N_NODES / 4, 256, 0, stream>>>(row, psrc, plg, x, outp);
}

// Round 3
// 312.992 us; speedup vs baseline: 5.4920x; 1.2581x over previous
//
#include <hip/hip_runtime.h>
#include <math.h>

#define N_NODES 40000
#define N_EDGES 640000
#define D 128
#define H 8
#define C 16
#define NB_SCAN 157  // ceil(40000/256)

// ws layout (float offsets):
//  x    : 0          .. 5,120,000   (N*128)
//  al   : 5,120,000  .. 5,440,000   (N*8)
//  ar   : 5,440,000  .. 5,760,000   (N*8)
//  plg  : 5,760,000  .. 10,880,000  (E*8, dst-sorted logits)
//  psrc : 10,880,000 .. 11,520,000  (E ints, dst-sorted src ids)
//  row  : 11,520,000 .. 11,560,001  (N+1 ints, CSR offsets)
//  cur  : 11,600,000 .. 11,640,000  (N ints, fill cursors)
//  cnt  : 11,700,000 .. 11,740,000  (N ints, histogram)
//  bsum : 11,800,000 .. +157        (block sums)
//  bpre : 11,810,000 .. +157        (block prefix)

// Fused: x = feat@Wlin ; res = feat@Wres -> d_out ; alpha_l/r head reductions.
__global__ __launch_bounds__(256) void k_fused_gemm(
    const float* __restrict__ feat, const float* __restrict__ Wlin,
    const float* __restrict__ Wres, const float* __restrict__ attl,
    const float* __restrict__ attr, float* __restrict__ x,
    float* __restrict__ al, float* __restrict__ ar, float* __restrict__ outp)
{
  __shared__ float sf[64 * 128];
  const int t = threadIdx.x;
  const long rowbase = (long)blockIdx.x * 64;

  const float4* fg = (const float4*)(feat + rowbase * 128);
  float4* sf4 = (float4*)sf;
  #pragma unroll
  for (int i = 0; i < 8; ++i) sf4[t + i * 256] = fg[t + i * 256];
  __syncthreads();

  float acc[64];
  #pragma unroll
  for (int r = 0; r < 64; ++r) acc[r] = 0.f;

  const float* W = (t < 128) ? (Wlin + t) : (Wres + (t - 128));
  for (int k = 0; k < 128; k += 4) {
    const float w0 = W[(k + 0) * 128];
    const float w1 = W[(k + 1) * 128];
    const float w2 = W[(k + 2) * 128];
    const float w3 = W[(k + 3) * 128];
    #pragma unroll
    for (int r = 0; r < 64; ++r) {
      const float4 f = *(const float4*)&sf[r * 128 + k];
      acc[r] = fmaf(f.w, w3, fmaf(f.z, w2, fmaf(f.y, w1, fmaf(f.x, w0, acc[r]))));
    }
  }
  __syncthreads();

  if (t < 128) {
    #pragma unroll
    for (int r = 0; r < 64; ++r) {
      x[(rowbase + r) * 128 + t] = acc[r];
      sf[r * 128 + t] = acc[r];
    }
  } else {
    #pragma unroll
    for (int r = 0; r < 64; ++r)
      outp[(rowbase + r) * 128 + (t - 128)] = acc[r];
  }
  __syncthreads();

  #pragma unroll
  for (int i = 0; i < 2; ++i) {
    const int task = t + i * 256;
    const int r = task >> 3, h = task & 7;
    float sl = 0.f, sr = 0.f;
    #pragma unroll
    for (int c = 0; c < 16; ++c) {
      const float xv = sf[r * 128 + h * 16 + c];
      sl = fmaf(xv, attl[h * 16 + c], sl);
      sr = fmaf(xv, attr[h * 16 + c], sr);
    }
    al[(rowbase + r) * 8 + h] = sl;
    ar[(rowbase + r) * 8 + h] = sr;
  }
}

__global__ __launch_bounds__(256) void k_hist(
    const int* __restrict__ dst, int* __restrict__ cnt)
{
  const int e = blockIdx.x * 256 + threadIdx.x;
  if (e >= N_EDGES) return;
  atomicAdd(&cnt[dst[e]], 1);
}

// Phase 1: per-block 256-wide scan; local exclusive prefix -> row, total -> bsum
__global__ __launch_bounds__(256) void k_scan_local(
    const int* __restrict__ cnt, int* __restrict__ row, int* __restrict__ bsum)
{
  __shared__ int sd[256];
  const int t = threadIdx.x;
  const int i = blockIdx.x * 256 + t;
  const int v = (i < N_NODES) ? cnt[i] : 0;
  sd[t] = v;
  __syncthreads();
  #pragma unroll
  for (int off = 1; off < 256; off <<= 1) {
    const int add = (t >= off) ? sd[t - off] : 0;
    __syncthreads();
    sd[t] += add;
    __syncthreads();
  }
  if (i < N_NODES) row[i] = sd[t] - v;       // local exclusive
  if (t == 255) bsum[blockIdx.x] = sd[255];  // block total
}

// Phase 2: single small block scans the 157 block totals -> exclusive bpre
__global__ __launch_bounds__(256) void k_scan_bsum(
    const int* __restrict__ bsum, int* __restrict__ bpre)
{
  __shared__ int sd[256];
  const int t = threadIdx.x;
  const int v = (t < NB_SCAN) ? bsum[t] : 0;
  sd[t] = v;
  __syncthreads();
  #pragma unroll
  for (int off = 1; off < 256; off <<= 1) {
    const int add = (t >= off) ? sd[t - off] : 0;
    __syncthreads();
    sd[t] += add;
    __syncthreads();
  }
  if (t < NB_SCAN) bpre[t] = sd[t] - v;      // exclusive
}

// Phase 3: add block prefix; write row and cur
__global__ __launch_bounds__(256) void k_scan_add(
    int* __restrict__ row, const int* __restrict__ bpre, int* __restrict__ cur)
{
  const int i = blockIdx.x * 256 + threadIdx.x;
  if (i < N_NODES) {
    const int r = row[i] + bpre[blockIdx.x];
    row[i] = r;
    cur[i] = r;
  }
  if (i == 0) row[N_NODES] = N_EDGES;
}

// Compute per-edge logits (leaky-relu'd) and scatter into dst-sorted order.
__global__ __launch_bounds__(256) void k_fill_logit(
    const int* __restrict__ src, const int* __restrict__ dst,
    const float* __restrict__ ew, const float* __restrict__ al,
    const float* __restrict__ ar, int* __restrict__ cur,
    float* __restrict__ plg, int* __restrict__ psrc)
{
  const int e = blockIdx.x * 256 + threadIdx.x;
  if (e >= N_EDGES) return;
  const int s = src[e], d = dst[e];
  const float w = ew[e];
  const float4 l0 = *(const float4*)&al[(long)s * 8];
  const float4 l1 = *(const float4*)&al[(long)s * 8 + 4];
  const float4 r0 = *(const float4*)&ar[(long)d * 8];
  const float4 r1 = *(const float4*)&ar[(long)d * 8 + 4];
  float lv[8] = {l0.x + r0.x, l0.y + r0.y, l0.z + r0.z, l0.w + r0.w,
                 l1.x + r1.x, l1.y + r1.y, l1.z + r1.z, l1.w + r1.w};
  #pragma unroll
  for (int h = 0; h < 8; ++h) {
    float a = w * lv[h];
    lv[h] = (a >= 0.f) ? a : 0.2f * a;   // leaky_relu(0.2)
  }
  const int p = atomicAdd(&cur[d], 1);
  psrc[p] = s;
  float4* o = (float4*)&plg[(long)p * 8];
  o[0] = make_float4(lv[0], lv[1], lv[2], lv[3]);
  o[1] = make_float4(lv[4], lv[5], lv[6], lv[7]);
}

// One wave per node: softmax (max+sum via xor-shuffles) + weighted gather
// of x[src] + elu + residual. Lane owns channels [2*lane, 2*lane+1].
__global__ __launch_bounds__(256) void k_node_agg(
    const int* __restrict__ row, const int* __restrict__ psrc,
    const float* __restrict__ plg, const float* __restrict__ x,
    float* __restrict__ outp)
{
  const int wave = threadIdx.x >> 6;
  const int lane = threadIdx.x & 63;
  const int d = blockIdx.x * 4 + wave;
  const int start = row[d], end = row[d + 1];
  const int deg = end - start;
  if (deg <= 0) return;  // out already holds residual; elu(0)=0

  const float* base = plg + (long)start * 8;
  const int nv = deg * 8;

  float m = -INFINITY;
  for (int v = lane; v < nv; v += 64) m = fmaxf(m, base[v]);
  m = fmaxf(m, __shfl_xor(m, 8));
  m = fmaxf(m, __shfl_xor(m, 16));
  m = fmaxf(m, __shfl_xor(m, 32));   // m = max for head (lane&7)

  float ssum = 0.f;
  for (int v = lane; v < nv; v += 64) ssum += __expf(base[v] - m);
  ssum += __shfl_xor(ssum, 8);
  ssum += __shfl_xor(ssum, 16);
  ssum += __shfl_xor(ssum, 32);      // denom for head (lane&7)

  const int h = lane >> 3;
  const float mh = __shfl(m, h);
  const float rs = 1.0f / __shfl(ssum, h);

  float2 acc = make_float2(0.f, 0.f);
  for (int i = 0; i < deg; ++i) {
    const long p = start + i;
    const float coef = __expf(plg[p * 8 + h] - mh) * rs;
    const int s = psrc[p];
    const float2 xv = *(const float2*)&x[(long)s * 128 + lane * 2];
    acc.x = fmaf(xv.x, coef, acc.x);
    acc.y = fmaf(xv.y, coef, acc.y);
  }

  float2 o = *(float2*)&outp[(long)d * 128 + lane * 2];
  o.x += (acc.x > 0.f) ? acc.x : expm1f(acc.x);
  o.y += (acc.y > 0.f) ? acc.y : expm1f(acc.y);
  *(float2*)&outp[(long)d * 128 + lane * 2] = o;
}

extern "C" void kernel_launch(void* const* d_in, const int* in_sizes, int n_in,
                              void* d_out, int out_size, void* d_ws, size_t ws_size,
                              hipStream_t stream) {
  const float* feat = (const float*)d_in[0];
  const int*   eidx = (const int*)d_in[1];
  const float* ew   = (const float*)d_in[2];
  const float* Wlin = (const float*)d_in[3];
  const float* attl = (const float*)d_in[4];
  const float* attr = (const float*)d_in[5];
  const float* Wres = (const float*)d_in[6];
  float* outp = (float*)d_out;

  float* ws = (float*)d_ws;
  float* x    = ws;
  float* al   = ws + 5120000;
  float* ar   = ws + 5440000;
  float* plg  = ws + 5760000;
  int*   psrc = (int*)(ws + 10880000);
  int*   row  = (int*)(ws + 11520000);
  int*   cur  = (int*)(ws + 11600000);
  int*   cnt  = (int*)(ws + 11700000);
  int*   bsum = (int*)(ws + 11800000);
  int*   bpre = (int*)(ws + 11810000);

  const int* src = eidx;
  const int* dst = eidx + N_EDGES;

  hipMemsetAsync(cnt, 0, (size_t)N_NODES * 4, stream);

  k_fused_gemm<<<N_NODES / 64, 256, 0, stream>>>(feat, Wlin, Wres, attl, attr,
                                                 x, al, ar, outp);
  k_hist<<<(N_EDGES + 255) / 256, 256, 0, stream>>>(dst, cnt);
  k_scan_local<<<NB_SCAN, 256, 0, stream>>>(cnt, row, bsum);
  k_scan_bsum<<<1, 256, 0, stream>>>(bsum, bpre);
  k_scan_add<<<NB_SCAN, 256, 0, stream>>>(row, bpre, cur);
  k_fill_logit<<<(N_EDGES + 255) / 256, 256, 0, stream>>>(src, dst, ew, al, ar,
                                                          cur, plg, psrc);
  k_node_agg<<<N_NODES / 4, 256, 0, stream>>>(row, psrc, plg, x, outp);
}

// Round 4
// 269.916 us; speedup vs baseline: 6.3685x; 1.1596x over previous
//
#include <hip/hip_runtime.h>
#include <math.h>

#define N_NODES 40000
#define N_EDGES 640000
#define D 128
#define H 8
#define C 16
#define NB_SCAN 157  // ceil(40000/256)
#define NB_GEMM 313  // ceil(40000/128)

// ws layout (float offsets):
//  x    : 0          .. 5,120,000   (N*128)
//  al   : 5,120,000  .. 5,440,000   (N*8)
//  ar   : 5,440,000  .. 5,760,000   (N*8)
//  plg  : 5,760,000  .. 10,880,000  (E*8, dst-sorted logits)
//  psrc : 10,880,000 .. 11,520,000  (E ints, dst-sorted src ids)
//  row  : 11,520,000 .. 11,560,001  (N+1 ints, CSR offsets)
//  cur  : 11,600,000 .. 11,640,000  (N ints, fill cursors)
//  cnt  : 11,700,000 .. 11,740,000  (N ints, histogram)
//  bsum : 11,800,000 .. +157        (block sums)
//  bpre : 11,810,000 .. +157        (block prefix)

// Register-tiled fp32 GEMM: 128x128 C-tile, 8x8 per thread, K-tile 32.
// blockIdx.y==0: x = feat@Wlin (+ alpha epilogue); ==1: outp = feat@Wres.
__global__ __launch_bounds__(256) void k_gemm(
    const float* __restrict__ feat, const float* __restrict__ Wlin,
    const float* __restrict__ Wres, const float* __restrict__ attl,
    const float* __restrict__ attr, float* __restrict__ x,
    float* __restrict__ al, float* __restrict__ ar, float* __restrict__ outp)
{
  __shared__ float smem[8192];   // 32 KB: sA = A^T tile 32x128, sB = 32x128
  float* sA = smem;              // sA[kk*128 + r]
  float* sB = smem + 4096;      // sB[kk*128 + c]

  const int t = threadIdx.x;
  const int tr = t >> 4, tc = t & 15;
  const int row0 = blockIdx.x * 128;
  const int isRes = blockIdx.y;
  const float* __restrict__ W = isRes ? Wres : Wlin;

  float acc[8][8];
  #pragma unroll
  for (int i = 0; i < 8; ++i)
    #pragma unroll
    for (int j = 0; j < 8; ++j) acc[i][j] = 0.f;

  for (int k0 = 0; k0 < 128; k0 += 32) {
    // A: 128 rows x 32 k = 1024 float4, transposed into sA[k][row]
    #pragma unroll
    for (int it = 0; it < 4; ++it) {
      const int v = t + it * 256;
      const int r = v >> 3, kq = v & 7;
      const int rr = min(row0 + r, N_NODES - 1);  // clamp tail
      const float4 f = *(const float4*)&feat[(long)rr * 128 + k0 + kq * 4];
      sA[(kq * 4 + 0) * 128 + r] = f.x;
      sA[(kq * 4 + 1) * 128 + r] = f.y;
      sA[(kq * 4 + 2) * 128 + r] = f.z;
      sA[(kq * 4 + 3) * 128 + r] = f.w;
    }
    // B: 32 k x 128 cols = 1024 float4, natural layout
    #pragma unroll
    for (int it = 0; it < 4; ++it) {
      const int v = t + it * 256;
      const int kk = v >> 5, cq = v & 31;
      *(float4*)&sB[kk * 128 + cq * 4] =
          *(const float4*)&W[(long)(k0 + kk) * 128 + cq * 4];
    }
    __syncthreads();
    #pragma unroll
    for (int kk = 0; kk < 32; ++kk) {
      const float4 a0 = *(const float4*)&sA[kk * 128 + tr * 8];
      const float4 a1 = *(const float4*)&sA[kk * 128 + tr * 8 + 4];
      const float4 b0 = *(const float4*)&sB[kk * 128 + tc * 8];
      const float4 b1 = *(const float4*)&sB[kk * 128 + tc * 8 + 4];
      const float av[8] = {a0.x, a0.y, a0.z, a0.w, a1.x, a1.y, a1.z, a1.w};
      const float bv[8] = {b0.x, b0.y, b0.z, b0.w, b1.x, b1.y, b1.z, b1.w};
      #pragma unroll
      for (int i = 0; i < 8; ++i)
        #pragma unroll
        for (int j = 0; j < 8; ++j)
          acc[i][j] = fmaf(av[i], bv[j], acc[i][j]);
    }
    __syncthreads();
  }

  float* dstp = isRes ? outp : x;
  #pragma unroll
  for (int i = 0; i < 8; ++i) {
    const int row = row0 + tr * 8 + i;
    if (row < N_NODES) {
      *(float4*)&dstp[(long)row * 128 + tc * 8] =
          make_float4(acc[i][0], acc[i][1], acc[i][2], acc[i][3]);
      *(float4*)&dstp[(long)row * 128 + tc * 8 + 4] =
          make_float4(acc[i][4], acc[i][5], acc[i][6], acc[i][7]);
    }
  }

  if (!isRes) {
    // alpha epilogue: this block holds all 128 cols of x for 128 rows.
    // thread's 8 cols lie in head h = tc/2, half = tc&1.
    const int h = tc >> 1, half = tc & 1;
    float wl[8], wr[8];
    #pragma unroll
    for (int j = 0; j < 8; ++j) {
      wl[j] = attl[h * 16 + half * 8 + j];
      wr[j] = attr[h * 16 + half * 8 + j];
    }
    float* pl = smem;           // [128][17] padded
    float* pr = smem + 2176;    // [128][17]
    #pragma unroll
    for (int i = 0; i < 8; ++i) {
      float sl = 0.f, sr = 0.f;
      #pragma unroll
      for (int j = 0; j < 8; ++j) {
        sl = fmaf(acc[i][j], wl[j], sl);
        sr = fmaf(acc[i][j], wr[j], sr);
      }
      pl[(tr * 8 + i) * 17 + tc] = sl;
      pr[(tr * 8 + i) * 17 + tc] = sr;
    }
    __syncthreads();
    #pragma unroll
    for (int it = 0; it < 8; ++it) {
      const int q = t + it * 256;     // [0,2048): 1024 l-tasks then 1024 r
      const int which = q >> 10;
      const int rem = q & 1023;
      const int row = rem >> 3, hh = rem & 7;
      const float* p = which ? pr : pl;
      const float v = p[row * 17 + hh * 2] + p[row * 17 + hh * 2 + 1];
      const int grow = row0 + row;
      if (grow < N_NODES)
        (which ? ar : al)[(long)grow * 8 + hh] = v;
    }
  }
}

__global__ __launch_bounds__(256) void k_hist(
    const int* __restrict__ dst, int* __restrict__ cnt)
{
  const int e = blockIdx.x * 256 + threadIdx.x;
  if (e >= N_EDGES) return;
  atomicAdd(&cnt[dst[e]], 1);
}

__global__ __launch_bounds__(256) void k_scan_local(
    const int* __restrict__ cnt, int* __restrict__ row, int* __restrict__ bsum)
{
  __shared__ int sd[256];
  const int t = threadIdx.x;
  const int i = blockIdx.x * 256 + t;
  const int v = (i < N_NODES) ? cnt[i] : 0;
  sd[t] = v;
  __syncthreads();
  #pragma unroll
  for (int off = 1; off < 256; off <<= 1) {
    const int add = (t >= off) ? sd[t - off] : 0;
    __syncthreads();
    sd[t] += add;
    __syncthreads();
  }
  if (i < N_NODES) row[i] = sd[t] - v;
  if (t == 255) bsum[blockIdx.x] = sd[255];
}

__global__ __launch_bounds__(256) void k_scan_bsum(
    const int* __restrict__ bsum, int* __restrict__ bpre)
{
  __shared__ int sd[256];
  const int t = threadIdx.x;
  const int v = (t < NB_SCAN) ? bsum[t] : 0;
  sd[t] = v;
  __syncthreads();
  #pragma unroll
  for (int off = 1; off < 256; off <<= 1) {
    const int add = (t >= off) ? sd[t - off] : 0;
    __syncthreads();
    sd[t] += add;
    __syncthreads();
  }
  if (t < NB_SCAN) bpre[t] = sd[t] - v;
}

__global__ __launch_bounds__(256) void k_scan_add(
    int* __restrict__ row, const int* __restrict__ bpre, int* __restrict__ cur)
{
  const int i = blockIdx.x * 256 + threadIdx.x;
  if (i < N_NODES) {
    const int r = row[i] + bpre[blockIdx.x];
    row[i] = r;
    cur[i] = r;
  }
  if (i == 0) row[N_NODES] = N_EDGES;
}

__global__ __launch_bounds__(256) void k_fill_logit(
    const int* __restrict__ src, const int* __restrict__ dst,
    const float* __restrict__ ew, const float* __restrict__ al,
    const float* __restrict__ ar, int* __restrict__ cur,
    float* __restrict__ plg, int* __restrict__ psrc)
{
  const int e = blockIdx.x * 256 + threadIdx.x;
  if (e >= N_EDGES) return;
  const int s = src[e], d = dst[e];
  const float w = ew[e];
  const float4 l0 = *(const float4*)&al[(long)s * 8];
  const float4 l1 = *(const float4*)&al[(long)s * 8 + 4];
  const float4 r0 = *(const float4*)&ar[(long)d * 8];
  const float4 r1 = *(const float4*)&ar[(long)d * 8 + 4];
  float lv[8] = {l0.x + r0.x, l0.y + r0.y, l0.z + r0.z, l0.w + r0.w,
                 l1.x + r1.x, l1.y + r1.y, l1.z + r1.z, l1.w + r1.w};
  #pragma unroll
  for (int h = 0; h < 8; ++h) {
    float a = w * lv[h];
    lv[h] = (a >= 0.f) ? a : 0.2f * a;   // leaky_relu(0.2)
  }
  const int p = atomicAdd(&cur[d], 1);
  psrc[p] = s;
  float4* o = (float4*)&plg[(long)p * 8];
  o[0] = make_float4(lv[0], lv[1], lv[2], lv[3]);
  o[1] = make_float4(lv[4], lv[5], lv[6], lv[7]);
}

// One wave per node: softmax (max+sum via xor-shuffles) + weighted gather.
__global__ __launch_bounds__(256) void k_node_agg(
    const int* __restrict__ row, const int* __restrict__ psrc,
    const float* __restrict__ plg, const float* __restrict__ x,
    float* __restrict__ outp)
{
  const int wave = threadIdx.x >> 6;
  const int lane = threadIdx.x & 63;
  const int d = blockIdx.x * 4 + wave;
  const int start = row[d], end = row[d + 1];
  const int deg = end - start;
  if (deg <= 0) return;

  const float* base = plg + (long)start * 8;
  const int nv = deg * 8;

  float m = -INFINITY;
  for (int v = lane; v < nv; v += 64) m = fmaxf(m, base[v]);
  m = fmaxf(m, __shfl_xor(m, 8));
  m = fmaxf(m, __shfl_xor(m, 16));
  m = fmaxf(m, __shfl_xor(m, 32));

  float ssum = 0.f;
  for (int v = lane; v < nv; v += 64) ssum += __expf(base[v] - m);
  ssum += __shfl_xor(ssum, 8);
  ssum += __shfl_xor(ssum, 16);
  ssum += __shfl_xor(ssum, 32);

  const int h = lane >> 3;
  const float mh = __shfl(m, h);
  const float rs = 1.0f / __shfl(ssum, h);

  float2 acc = make_float2(0.f, 0.f);
  for (int i = 0; i < deg; ++i) {
    const long p = start + i;
    const float coef = __expf(plg[p * 8 + h] - mh) * rs;
    const int s = psrc[p];
    const float2 xv = *(const float2*)&x[(long)s * 128 + lane * 2];
    acc.x = fmaf(xv.x, coef, acc.x);
    acc.y = fmaf(xv.y, coef, acc.y);
  }

  float2 o = *(float2*)&outp[(long)d * 128 + lane * 2];
  o.x += (acc.x > 0.f) ? acc.x : expm1f(acc.x);
  o.y += (acc.y > 0.f) ? acc.y : expm1f(acc.y);
  *(float2*)&outp[(long)d * 128 + lane * 2] = o;
}

extern "C" void kernel_launch(void* const* d_in, const int* in_sizes, int n_in,
                              void* d_out, int out_size, void* d_ws, size_t ws_size,
                              hipStream_t stream) {
  const float* feat = (const float*)d_in[0];
  const int*   eidx = (const int*)d_in[1];
  const float* ew   = (const float*)d_in[2];
  const float* Wlin = (const float*)d_in[3];
  const float* attl = (const float*)d_in[4];
  const float* attr = (const float*)d_in[5];
  const float* Wres = (const float*)d_in[6];
  float* outp = (float*)d_out;

  float* ws = (float*)d_ws;
  float* x    = ws;
  float* al   = ws + 5120000;
  float* ar   = ws + 5440000;
  float* plg  = ws + 5760000;
  int*   psrc = (int*)(ws + 10880000);
  int*   row  = (int*)(ws + 11520000);
  int*   cur  = (int*)(ws + 11600000);
  int*   cnt  = (int*)(ws + 11700000);
  int*   bsum = (int*)(ws + 11800000);
  int*   bpre = (int*)(ws + 11810000);

  const int* src = eidx;
  const int* dst = eidx + N_EDGES;

  hipMemsetAsync(cnt, 0, (size_t)N_NODES * 4, stream);

  dim3 ggrid(NB_GEMM, 2);
  k_gemm<<<ggrid, 256, 0, stream>>>(feat, Wlin, Wres, attl, attr, x, al, ar, outp);
  k_hist<<<(N_EDGES + 255) / 256, 256, 0, stream>>>(dst, cnt);
  k_scan_local<<<NB_SCAN, 256, 0, stream>>>(cnt, row, bsum);
  k_scan_bsum<<<1, 256, 0, stream>>>(bsum, bpre);
  k_scan_add<<<NB_SCAN, 256, 0, stream>>>(row, bpre, cur);
  k_fill_logit<<<(N_EDGES + 255) / 256, 256, 0, stream>>>(src, dst, ew, al, ar,
                                                          cur, plg, psrc);
  k_node_agg<<<N_NODES / 4, 256, 0, stream>>>(row, psrc, plg, x, outp);
}

// Round 5
// 236.181 us; speedup vs baseline: 7.2781x; 1.1428x over previous
//
#include <hip/hip_runtime.h>
#include <math.h>

#define N_NODES 40000
#define N_EDGES 640000
#define D 128
#define H 8
#define C 16
#define NB_SCAN 157  // ceil(40000/256)
#define NB_GEMM 313  // ceil(40000/128)

// ws layout (float offsets):
//  xh   : 0          .. 2,560,000   (N*128 bf16 stored as ushort)
//  al   : 5,120,000  .. 5,440,000   (N*8)
//  ar   : 5,440,000  .. 5,760,000   (N*8)
//  plg  : 5,760,000  .. 10,880,000  (E*8, dst-sorted logits)
//  psrc : 10,880,000 .. 11,520,000  (E ints, dst-sorted src ids)
//  row  : 11,520,000 .. 11,560,001  (N+1 ints, CSR offsets)
//  cur  : 11,600,000 .. 11,640,000  (N ints, fill cursors)
//  cnt  : 11,700,000 .. 11,740,000  (N ints, histogram)
//  bsum : 11,800,000 .. +157
//  bpre : 11,810,000 .. +157

__device__ __forceinline__ unsigned short f2bf(float f) {
  const unsigned u = __float_as_uint(f);
  return (unsigned short)((u + 0x7FFFu + ((u >> 16) & 1u)) >> 16);  // RNE
}
__device__ __forceinline__ float bflo(unsigned p) {
  return __uint_as_float(p << 16);
}
__device__ __forceinline__ float bfhi(unsigned p) {
  return __uint_as_float(p & 0xFFFF0000u);
}

// Register-tiled fp32 GEMM: 128x128 C-tile, 8x8 per thread, K-tile 32.
// blockIdx.y==0: xh = bf16(feat@Wlin) (+ alpha epilogue); ==1: outp = feat@Wres.
__global__ __launch_bounds__(256) void k_gemm(
    const float* __restrict__ feat, const float* __restrict__ Wlin,
    const float* __restrict__ Wres, const float* __restrict__ attl,
    const float* __restrict__ attr, unsigned short* __restrict__ xh,
    float* __restrict__ al, float* __restrict__ ar, float* __restrict__ outp)
{
  __shared__ float smem[8192];   // 32 KB: sA = A^T tile 32x128, sB = 32x128
  float* sA = smem;
  float* sB = smem + 4096;

  const int t = threadIdx.x;
  const int tr = t >> 4, tc = t & 15;
  const int row0 = blockIdx.x * 128;
  const int isRes = blockIdx.y;
  const float* __restrict__ W = isRes ? Wres : Wlin;

  float acc[8][8];
  #pragma unroll
  for (int i = 0; i < 8; ++i)
    #pragma unroll
    for (int j = 0; j < 8; ++j) acc[i][j] = 0.f;

  for (int k0 = 0; k0 < 128; k0 += 32) {
    #pragma unroll
    for (int it = 0; it < 4; ++it) {
      const int v = t + it * 256;
      const int r = v >> 3, kq = v & 7;
      const int rr = min(row0 + r, N_NODES - 1);
      const float4 f = *(const float4*)&feat[(long)rr * 128 + k0 + kq * 4];
      sA[(kq * 4 + 0) * 128 + r] = f.x;
      sA[(kq * 4 + 1) * 128 + r] = f.y;
      sA[(kq * 4 + 2) * 128 + r] = f.z;
      sA[(kq * 4 + 3) * 128 + r] = f.w;
    }
    #pragma unroll
    for (int it = 0; it < 4; ++it) {
      const int v = t + it * 256;
      const int kk = v >> 5, cq = v & 31;
      *(float4*)&sB[kk * 128 + cq * 4] =
          *(const float4*)&W[(long)(k0 + kk) * 128 + cq * 4];
    }
    __syncthreads();
    #pragma unroll
    for (int kk = 0; kk < 32; ++kk) {
      const float4 a0 = *(const float4*)&sA[kk * 128 + tr * 8];
      const float4 a1 = *(const float4*)&sA[kk * 128 + tr * 8 + 4];
      const float4 b0 = *(const float4*)&sB[kk * 128 + tc * 8];
      const float4 b1 = *(const float4*)&sB[kk * 128 + tc * 8 + 4];
      const float av[8] = {a0.x, a0.y, a0.z, a0.w, a1.x, a1.y, a1.z, a1.w};
      const float bv[8] = {b0.x, b0.y, b0.z, b0.w, b1.x, b1.y, b1.z, b1.w};
      #pragma unroll
      for (int i = 0; i < 8; ++i)
        #pragma unroll
        for (int j = 0; j < 8; ++j)
          acc[i][j] = fmaf(av[i], bv[j], acc[i][j]);
    }
    __syncthreads();
  }

  if (isRes) {
    #pragma unroll
    for (int i = 0; i < 8; ++i) {
      const int row = row0 + tr * 8 + i;
      if (row < N_NODES) {
        *(float4*)&outp[(long)row * 128 + tc * 8] =
            make_float4(acc[i][0], acc[i][1], acc[i][2], acc[i][3]);
        *(float4*)&outp[(long)row * 128 + tc * 8 + 4] =
            make_float4(acc[i][4], acc[i][5], acc[i][6], acc[i][7]);
      }
    }
  } else {
    #pragma unroll
    for (int i = 0; i < 8; ++i) {
      const int row = row0 + tr * 8 + i;
      if (row < N_NODES) {
        uint4 w;
        w.x = (unsigned)f2bf(acc[i][0]) | ((unsigned)f2bf(acc[i][1]) << 16);
        w.y = (unsigned)f2bf(acc[i][2]) | ((unsigned)f2bf(acc[i][3]) << 16);
        w.z = (unsigned)f2bf(acc[i][4]) | ((unsigned)f2bf(acc[i][5]) << 16);
        w.w = (unsigned)f2bf(acc[i][6]) | ((unsigned)f2bf(acc[i][7]) << 16);
        *(uint4*)&xh[(long)row * 128 + tc * 8] = w;
      }
    }
    // alpha epilogue (fp32 acc): thread's 8 cols = head h = tc/2, half = tc&1
    const int h = tc >> 1, half = tc & 1;
    float wl[8], wr[8];
    #pragma unroll
    for (int j = 0; j < 8; ++j) {
      wl[j] = attl[h * 16 + half * 8 + j];
      wr[j] = attr[h * 16 + half * 8 + j];
    }
    float* pl = smem;           // [128][17] padded
    float* pr = smem + 2176;
    #pragma unroll
    for (int i = 0; i < 8; ++i) {
      float sl = 0.f, sr = 0.f;
      #pragma unroll
      for (int j = 0; j < 8; ++j) {
        sl = fmaf(acc[i][j], wl[j], sl);
        sr = fmaf(acc[i][j], wr[j], sr);
      }
      pl[(tr * 8 + i) * 17 + tc] = sl;
      pr[(tr * 8 + i) * 17 + tc] = sr;
    }
    __syncthreads();
    #pragma unroll
    for (int it = 0; it < 8; ++it) {
      const int q = t + it * 256;
      const int which = q >> 10;
      const int rem = q & 1023;
      const int row = rem >> 3, hh = rem & 7;
      const float* p = which ? pr : pl;
      const float v = p[row * 17 + hh * 2] + p[row * 17 + hh * 2 + 1];
      const int grow = row0 + row;
      if (grow < N_NODES)
        (which ? ar : al)[(long)grow * 8 + hh] = v;
    }
  }
}

__global__ __launch_bounds__(256) void k_hist(
    const int* __restrict__ dst, int* __restrict__ cnt)
{
  const int e = blockIdx.x * 256 + threadIdx.x;
  if (e >= N_EDGES) return;
  atomicAdd(&cnt[dst[e]], 1);
}

__global__ __launch_bounds__(256) void k_scan_local(
    const int* __restrict__ cnt, int* __restrict__ row, int* __restrict__ bsum)
{
  __shared__ int sd[256];
  const int t = threadIdx.x;
  const int i = blockIdx.x * 256 + t;
  const int v = (i < N_NODES) ? cnt[i] : 0;
  sd[t] = v;
  __syncthreads();
  #pragma unroll
  for (int off = 1; off < 256; off <<= 1) {
    const int add = (t >= off) ? sd[t - off] : 0;
    __syncthreads();
    sd[t] += add;
    __syncthreads();
  }
  if (i < N_NODES) row[i] = sd[t] - v;
  if (t == 255) bsum[blockIdx.x] = sd[255];
}

__global__ __launch_bounds__(256) void k_scan_bsum(
    const int* __restrict__ bsum, int* __restrict__ bpre)
{
  __shared__ int sd[256];
  const int t = threadIdx.x;
  const int v = (t < NB_SCAN) ? bsum[t] : 0;
  sd[t] = v;
  __syncthreads();
  #pragma unroll
  for (int off = 1; off < 256; off <<= 1) {
    const int add = (t >= off) ? sd[t - off] : 0;
    __syncthreads();
    sd[t] += add;
    __syncthreads();
  }
  if (t < NB_SCAN) bpre[t] = sd[t] - v;
}

__global__ __launch_bounds__(256) void k_scan_add(
    int* __restrict__ row, const int* __restrict__ bpre, int* __restrict__ cur)
{
  const int i = blockIdx.x * 256 + threadIdx.x;
  if (i < N_NODES) {
    const int r = row[i] + bpre[blockIdx.x];
    row[i] = r;
    cur[i] = r;
  }
  if (i == 0) row[N_NODES] = N_EDGES;
}

__global__ __launch_bounds__(256) void k_fill_logit(
    const int* __restrict__ src, const int* __restrict__ dst,
    const float* __restrict__ ew, const float* __restrict__ al,
    const float* __restrict__ ar, int* __restrict__ cur,
    float* __restrict__ plg, int* __restrict__ psrc)
{
  const int e = blockIdx.x * 256 + threadIdx.x;
  if (e >= N_EDGES) return;
  const int s = src[e], d = dst[e];
  const float w = ew[e];
  const float4 l0 = *(const float4*)&al[(long)s * 8];
  const float4 l1 = *(const float4*)&al[(long)s * 8 + 4];
  const float4 r0 = *(const float4*)&ar[(long)d * 8];
  const float4 r1 = *(const float4*)&ar[(long)d * 8 + 4];
  float lv[8] = {l0.x + r0.x, l0.y + r0.y, l0.z + r0.z, l0.w + r0.w,
                 l1.x + r1.x, l1.y + r1.y, l1.z + r1.z, l1.w + r1.w};
  #pragma unroll
  for (int h = 0; h < 8; ++h) {
    float a = w * lv[h];
    lv[h] = (a >= 0.f) ? a : 0.2f * a;   // leaky_relu(0.2)
  }
  const int p = atomicAdd(&cur[d], 1);
  psrc[p] = s;
  float4* o = (float4*)&plg[(long)p * 8];
  o[0] = make_float4(lv[0], lv[1], lv[2], lv[3]);
  o[1] = make_float4(lv[4], lv[5], lv[6], lv[7]);
}

// One wave per node: softmax via xor-shuffles, then x4-unrolled weighted
// gather of bf16 x rows (4 independent load chains for MLP). Zero atomics.
__global__ __launch_bounds__(256) void k_node_agg(
    const int* __restrict__ row, const int* __restrict__ psrc,
    const float* __restrict__ plg, const unsigned short* __restrict__ xh,
    float* __restrict__ outp)
{
  const int wave = threadIdx.x >> 6;
  const int lane = threadIdx.x & 63;
  const int d = blockIdx.x * 4 + wave;
  const int start = row[d], end = row[d + 1];
  const int deg = end - start;
  if (deg <= 0) return;

  const float* base = plg + (long)start * 8;
  const int nv = deg * 8;

  float m = -INFINITY;
  for (int v = lane; v < nv; v += 64) m = fmaxf(m, base[v]);
  m = fmaxf(m, __shfl_xor(m, 8));
  m = fmaxf(m, __shfl_xor(m, 16));
  m = fmaxf(m, __shfl_xor(m, 32));   // per-head max (head = lane&7)

  float ssum = 0.f;
  for (int v = lane; v < nv; v += 64) ssum += __expf(base[v] - m);
  ssum += __shfl_xor(ssum, 8);
  ssum += __shfl_xor(ssum, 16);
  ssum += __shfl_xor(ssum, 32);      // per-head denom

  const int h = lane >> 3;
  const float mh = __shfl(m, h);
  const float rs = 1.0f / __shfl(ssum, h);

  const int co = lane * 2;           // my 2 channels
  float2 a0 = {0.f, 0.f}, a1 = {0.f, 0.f}, a2 = {0.f, 0.f}, a3 = {0.f, 0.f};
  int p = start;
  for (; p + 4 <= end; p += 4) {
    const int s0 = psrc[p + 0], s1 = psrc[p + 1];
    const int s2 = psrc[p + 2], s3 = psrc[p + 3];
    const float e0 = __expf(plg[(long)(p + 0) * 8 + h] - mh);
    const float e1 = __expf(plg[(long)(p + 1) * 8 + h] - mh);
    const float e2 = __expf(plg[(long)(p + 2) * 8 + h] - mh);
    const float e3 = __expf(plg[(long)(p + 3) * 8 + h] - mh);
    const unsigned v0 = *(const unsigned*)&xh[(long)s0 * 128 + co];
    const unsigned v1 = *(const unsigned*)&xh[(long)s1 * 128 + co];
    const unsigned v2 = *(const unsigned*)&xh[(long)s2 * 128 + co];
    const unsigned v3 = *(const unsigned*)&xh[(long)s3 * 128 + co];
    a0.x = fmaf(bflo(v0), e0, a0.x); a0.y = fmaf(bfhi(v0), e0, a0.y);
    a1.x = fmaf(bflo(v1), e1, a1.x); a1.y = fmaf(bfhi(v1), e1, a1.y);
    a2.x = fmaf(bflo(v2), e2, a2.x); a2.y = fmaf(bfhi(v2), e2, a2.y);
    a3.x = fmaf(bflo(v3), e3, a3.x); a3.y = fmaf(bfhi(v3), e3, a3.y);
  }
  for (; p < end; ++p) {
    const int s = psrc[p];
    const float e0 = __expf(plg[(long)p * 8 + h] - mh);
    const unsigned v = *(const unsigned*)&xh[(long)s * 128 + co];
    a0.x = fmaf(bflo(v), e0, a0.x);
    a0.y = fmaf(bfhi(v), e0, a0.y);
  }
  const float ax = ((a0.x + a1.x) + (a2.x + a3.x)) * rs;
  const float ay = ((a0.y + a1.y) + (a2.y + a3.y)) * rs;

  float2 o = *(float2*)&outp[(long)d * 128 + co];
  o.x += (ax > 0.f) ? ax : expm1f(ax);
  o.y += (ay > 0.f) ? ay : expm1f(ay);
  *(float2*)&outp[(long)d * 128 + co] = o;
}

extern "C" void kernel_launch(void* const* d_in, const int* in_sizes, int n_in,
                              void* d_out, int out_size, void* d_ws, size_t ws_size,
                              hipStream_t stream) {
  const float* feat = (const float*)d_in[0];
  const int*   eidx = (const int*)d_in[1];
  const float* ew   = (const float*)d_in[2];
  const float* Wlin = (const float*)d_in[3];
  const float* attl = (const float*)d_in[4];
  const float* attr = (const float*)d_in[5];
  const float* Wres = (const float*)d_in[6];
  float* outp = (float*)d_out;

  float* ws = (float*)d_ws;
  unsigned short* xh = (unsigned short*)ws;
  float* al   = ws + 5120000;
  float* ar   = ws + 5440000;
  float* plg  = ws + 5760000;
  int*   psrc = (int*)(ws + 10880000);
  int*   row  = (int*)(ws + 11520000);
  int*   cur  = (int*)(ws + 11600000);
  int*   cnt  = (int*)(ws + 11700000);
  int*   bsum = (int*)(ws + 11800000);
  int*   bpre = (int*)(ws + 11810000);

  const int* src = eidx;
  const int* dst = eidx + N_EDGES;

  hipMemsetAsync(cnt, 0, (size_t)N_NODES * 4, stream);

  dim3 ggrid(NB_GEMM, 2);
  k_gemm<<<ggrid, 256, 0, stream>>>(feat, Wlin, Wres, attl, attr, xh, al, ar, outp);
  k_hist<<<(N_EDGES + 255) / 256, 256, 0, stream>>>(dst, cnt);
  k_scan_local<<<NB_SCAN, 256, 0, stream>>>(cnt, row, bsum);
  k_scan_bsum<<<1, 256, 0, stream>>>(bsum, bpre);
  k_scan_add<<<NB_SCAN, 256, 0, stream>>>(row, bpre, cur);
  k_fill_logit<<<(N_EDGES + 255) / 256, 256, 0, stream>>>(src, dst, ew, al, ar,
                                                          cur, plg, psrc);
  k_node_agg<<<N_NODES / 4, 256, 0, stream>>>(row, psrc, plg, xh, outp);
}

// Round 6
// 205.132 us; speedup vs baseline: 8.3797x; 1.1514x over previous
//
#include <hip/hip_runtime.h>
#include <math.h>

#define N_NODES 40000
#define N_EDGES 640000
#define D 128
#define H 8
#define C 16
#define NB_SCAN 157  // ceil(40000/256)
#define NB_GEMM 313  // ceil(40000/128)
#define SA 132       // padded sA stride (floats): transpose writes 8-way -> 4-way

// ws layout (float offsets):
//  xh   : 0          .. 2,560,000   (N*128 bf16 stored as ushort)
//  al   : 5,120,000  .. 5,440,000   (N*8)
//  ar   : 5,440,000  .. 5,760,000   (N*8)
//  plg  : 5,760,000  .. 10,880,000  (E*8, dst-sorted logits)
//  psrc : 10,880,000 .. 11,520,000  (E ints, dst-sorted src ids)
//  rowL : 11,520,000 .. 11,560,000  (N ints, LOCAL exclusive prefix)
//  cnt  : 11,700,000 .. 11,740,000  (N ints, histogram)   | zeroed together
//  cur  : 11,740,000 .. 11,780,000  (N ints, fill cursors) | (one memset)
//  bsum : 11,800,000 .. +157
//  bpre : 11,810,000 .. +157

__device__ __forceinline__ unsigned short f2bf(float f) {
  const unsigned u = __float_as_uint(f);
  return (unsigned short)((u + 0x7FFFu + ((u >> 16) & 1u)) >> 16);  // RNE
}
__device__ __forceinline__ float bflo(unsigned p) {
  return __uint_as_float(p << 16);
}
__device__ __forceinline__ float bfhi(unsigned p) {
  return __uint_as_float(p & 0xFFFF0000u);
}

// Register-tiled fp32 GEMM, 128x128 C-tile, 8x8/thread with 4+4 split
// fragments (rows tr*4,+64; cols tc*4,+64) for conflict-free LDS reads.
// blockIdx.y: 0 = xh=bf16(feat@Wlin)+alpha epilogue; 1 = outp=feat@Wres;
//             2 = fused dst-histogram (overlaps with gemm work).
__global__ __launch_bounds__(256) void k_gemm(
    const float* __restrict__ feat, const float* __restrict__ Wlin,
    const float* __restrict__ Wres, const float* __restrict__ attl,
    const float* __restrict__ attr, unsigned short* __restrict__ xh,
    float* __restrict__ al, float* __restrict__ ar, float* __restrict__ outp,
    const int* __restrict__ dst, int* __restrict__ cnt)
{
  __shared__ float smem[8320];   // sA 32*132=4224 | sB 4096 ; epilogue reuse 8192
  const int t = threadIdx.x;

  if (blockIdx.y == 2) {         // fused histogram
    const int stride = NB_GEMM * 256;
    for (int e = blockIdx.x * 256 + t; e < N_EDGES; e += stride)
      atomicAdd(&cnt[dst[e]], 1);
    return;
  }

  float* sA = smem;              // sA[k][r], stride SA
  float* sB = smem + 4224;       // sB[k][c], stride 128

  const int tr = t >> 4, tc = t & 15;
  const int row0 = blockIdx.x * 128;
  const int isRes = blockIdx.y;
  const float* __restrict__ W = isRes ? Wres : Wlin;

  float acc[8][8];
  #pragma unroll
  for (int i = 0; i < 8; ++i)
    #pragma unroll
    for (int j = 0; j < 8; ++j) acc[i][j] = 0.f;

  for (int k0 = 0; k0 < 128; k0 += 32) {
    // A: 128 rows x 32 k, transposed into sA[k][r] (4-way write conflicts w/ pad)
    #pragma unroll
    for (int it = 0; it < 4; ++it) {
      const int v = t + it * 256;
      const int r = v >> 3, kq = v & 7;
      const int rr = min(row0 + r, N_NODES - 1);
      const float4 f = *(const float4*)&feat[(long)rr * 128 + k0 + kq * 4];
      sA[(kq * 4 + 0) * SA + r] = f.x;
      sA[(kq * 4 + 1) * SA + r] = f.y;
      sA[(kq * 4 + 2) * SA + r] = f.z;
      sA[(kq * 4 + 3) * SA + r] = f.w;
    }
    // B: natural layout, conflict-free float4 writes
    #pragma unroll
    for (int it = 0; it < 4; ++it) {
      const int v = t + it * 256;
      const int kk = v >> 5, cq = v & 31;
      *(float4*)&sB[kk * 128 + cq * 4] =
          *(const float4*)&W[(long)(k0 + kk) * 128 + cq * 4];
    }
    __syncthreads();
    #pragma unroll
    for (int kk = 0; kk < 32; ++kk) {
      const float4 alo = *(const float4*)&sA[kk * SA + tr * 4];
      const float4 ahi = *(const float4*)&sA[kk * SA + 64 + tr * 4];
      const float4 blo = *(const float4*)&sB[kk * 128 + tc * 4];
      const float4 bhi = *(const float4*)&sB[kk * 128 + 64 + tc * 4];
      const float av[8] = {alo.x, alo.y, alo.z, alo.w, ahi.x, ahi.y, ahi.z, ahi.w};
      const float bv[8] = {blo.x, blo.y, blo.z, blo.w, bhi.x, bhi.y, bhi.z, bhi.w};
      #pragma unroll
      for (int i = 0; i < 8; ++i)
        #pragma unroll
        for (int j = 0; j < 8; ++j)
          acc[i][j] = fmaf(av[i], bv[j], acc[i][j]);
    }
    __syncthreads();
  }

  // C write: rows tr*4+(i&3)+(i>>2)*64; cols tc*4 (j 0-3) and 64+tc*4 (j 4-7)
  if (isRes) {
    #pragma unroll
    for (int i = 0; i < 8; ++i) {
      const int row = row0 + tr * 4 + (i & 3) + (i >> 2) * 64;
      if (row < N_NODES) {
        *(float4*)&outp[(long)row * 128 + tc * 4] =
            make_float4(acc[i][0], acc[i][1], acc[i][2], acc[i][3]);
        *(float4*)&outp[(long)row * 128 + 64 + tc * 4] =
            make_float4(acc[i][4], acc[i][5], acc[i][6], acc[i][7]);
      }
    }
  } else {
    #pragma unroll
    for (int i = 0; i < 8; ++i) {
      const int row = row0 + tr * 4 + (i & 3) + (i >> 2) * 64;
      if (row < N_NODES) {
        uint2 wlo, whi;
        wlo.x = (unsigned)f2bf(acc[i][0]) | ((unsigned)f2bf(acc[i][1]) << 16);
        wlo.y = (unsigned)f2bf(acc[i][2]) | ((unsigned)f2bf(acc[i][3]) << 16);
        whi.x = (unsigned)f2bf(acc[i][4]) | ((unsigned)f2bf(acc[i][5]) << 16);
        whi.y = (unsigned)f2bf(acc[i][6]) | ((unsigned)f2bf(acc[i][7]) << 16);
        *(uint2*)&xh[(long)row * 128 + tc * 4] = wlo;
        *(uint2*)&xh[(long)row * 128 + 64 + tc * 4] = whi;
      }
    }
    // alpha epilogue: cols tc*4..+3 lie in head h1=tc>>2 quarter q=tc&3;
    // cols 64+tc*4..+3 in head h2=4+(tc>>2) same quarter.
    const int q = tc & 3, h1 = tc >> 2, h2 = 4 + (tc >> 2);
    float wl1[4], wr1[4], wl2[4], wr2[4];
    #pragma unroll
    for (int j = 0; j < 4; ++j) {
      wl1[j] = attl[h1 * 16 + q * 4 + j];
      wr1[j] = attr[h1 * 16 + q * 4 + j];
      wl2[j] = attl[h2 * 16 + q * 4 + j];
      wr2[j] = attr[h2 * 16 + q * 4 + j];
    }
    float* pl = smem;           // [128 rows][8 heads][4 quarters]
    float* pr = smem + 4096;
    #pragma unroll
    for (int i = 0; i < 8; ++i) {
      const int r = tr * 4 + (i & 3) + (i >> 2) * 64;
      float sl1 = 0.f, sr1 = 0.f, sl2 = 0.f, sr2 = 0.f;
      #pragma unroll
      for (int j = 0; j < 4; ++j) {
        sl1 = fmaf(acc[i][j], wl1[j], sl1);
        sr1 = fmaf(acc[i][j], wr1[j], sr1);
        sl2 = fmaf(acc[i][j + 4], wl2[j], sl2);
        sr2 = fmaf(acc[i][j + 4], wr2[j], sr2);
      }
      pl[(r * 8 + h1) * 4 + q] = sl1;
      pl[(r * 8 + h2) * 4 + q] = sl2;
      pr[(r * 8 + h1) * 4 + q] = sr1;
      pr[(r * 8 + h2) * 4 + q] = sr2;
    }
    __syncthreads();
    #pragma unroll
    for (int it = 0; it < 8; ++it) {
      const int task = t + it * 256;   // 2048: (which, row, head)
      const int which = task >> 10;
      const int rem = task & 1023;
      const int r = rem >> 3, hh = rem & 7;
      const float4 v4 = *(const float4*)&(which ? pr : pl)[(r * 8 + hh) * 4];
      const float v = (v4.x + v4.y) + (v4.z + v4.w);
      const int grow = row0 + r;
      if (grow < N_NODES)
        (which ? ar : al)[(long)grow * 8 + hh] = v;
    }
  }
}

// Per-block local exclusive scan of cnt; totals to bsum. (Global offset is
// bpre[block], folded into consumers — no scan_add pass.)
__global__ __launch_bounds__(256) void k_scan_local(
    const int* __restrict__ cnt, int* __restrict__ rowL, int* __restrict__ bsum)
{
  __shared__ int sd[256];
  const int t = threadIdx.x;
  const int i = blockIdx.x * 256 + t;
  const int v = (i < N_NODES) ? cnt[i] : 0;
  sd[t] = v;
  __syncthreads();
  #pragma unroll
  for (int off = 1; off < 256; off <<= 1) {
    const int add = (t >= off) ? sd[t - off] : 0;
    __syncthreads();
    sd[t] += add;
    __syncthreads();
  }
  if (i < N_NODES) rowL[i] = sd[t] - v;
  if (t == 255) bsum[blockIdx.x] = sd[255];
}

__global__ __launch_bounds__(256) void k_scan_bsum(
    const int* __restrict__ bsum, int* __restrict__ bpre)
{
  __shared__ int sd[256];
  const int t = threadIdx.x;
  const int v = (t < NB_SCAN) ? bsum[t] : 0;
  sd[t] = v;
  __syncthreads();
  #pragma unroll
  for (int off = 1; off < 256; off <<= 1) {
    const int add = (t >= off) ? sd[t - off] : 0;
    __syncthreads();
    sd[t] += add;
    __syncthreads();
  }
  if (t < NB_SCAN) bpre[t] = sd[t] - v;
}

__global__ __launch_bounds__(256) void k_fill_logit(
    const int* __restrict__ src, const int* __restrict__ dst,
    const float* __restrict__ ew, const float* __restrict__ al,
    const float* __restrict__ ar, const int* __restrict__ rowL,
    const int* __restrict__ bpre, int* __restrict__ cur,
    float* __restrict__ plg, int* __restrict__ psrc)
{
  const int e = blockIdx.x * 256 + threadIdx.x;
  if (e >= N_EDGES) return;
  const int s = src[e], d = dst[e];
  const float w = ew[e];
  const float4 l0 = *(const float4*)&al[(long)s * 8];
  const float4 l1 = *(const float4*)&al[(long)s * 8 + 4];
  const float4 r0 = *(const float4*)&ar[(long)d * 8];
  const float4 r1 = *(const float4*)&ar[(long)d * 8 + 4];
  float lv[8] = {l0.x + r0.x, l0.y + r0.y, l0.z + r0.z, l0.w + r0.w,
                 l1.x + r1.x, l1.y + r1.y, l1.z + r1.z, l1.w + r1.w};
  #pragma unroll
  for (int h = 0; h < 8; ++h) {
    float a = w * lv[h];
    lv[h] = (a >= 0.f) ? a : 0.2f * a;   // leaky_relu(0.2)
  }
  const int p = rowL[d] + bpre[d >> 8] + atomicAdd(&cur[d], 1);
  psrc[p] = s;
  float4* o = (float4*)&plg[(long)p * 8];
  o[0] = make_float4(lv[0], lv[1], lv[2], lv[3]);
  o[1] = make_float4(lv[4], lv[5], lv[6], lv[7]);
}

// One wave per node: softmax via xor-shuffles, x4-unrolled bf16 gather.
__global__ __launch_bounds__(256) void k_node_agg(
    const int* __restrict__ rowL, const int* __restrict__ bpre,
    const int* __restrict__ psrc, const float* __restrict__ plg,
    const unsigned short* __restrict__ xh, float* __restrict__ outp)
{
  const int wave = threadIdx.x >> 6;
  const int lane = threadIdx.x & 63;
  const int d = blockIdx.x * 4 + wave;
  const int start = rowL[d] + bpre[d >> 8];
  const int dn = d + 1;
  const int end = (dn == N_NODES) ? N_EDGES : (rowL[dn] + bpre[dn >> 8]);
  const int deg = end - start;
  if (deg <= 0) return;   // out already holds residual; elu(0)=0

  const float* base = plg + (long)start * 8;
  const int nv = deg * 8;

  float m = -INFINITY;
  for (int v = lane; v < nv; v += 64) m = fmaxf(m, base[v]);
  m = fmaxf(m, __shfl_xor(m, 8));
  m = fmaxf(m, __shfl_xor(m, 16));
  m = fmaxf(m, __shfl_xor(m, 32));   // per-head max (head = lane&7)

  float ssum = 0.f;
  for (int v = lane; v < nv; v += 64) ssum += __expf(base[v] - m);
  ssum += __shfl_xor(ssum, 8);
  ssum += __shfl_xor(ssum, 16);
  ssum += __shfl_xor(ssum, 32);      // per-head denom

  const int h = lane >> 3;
  const float mh = __shfl(m, h);
  const float rs = 1.0f / __shfl(ssum, h);

  const int co = lane * 2;
  float2 a0 = {0.f, 0.f}, a1 = {0.f, 0.f}, a2 = {0.f, 0.f}, a3 = {0.f, 0.f};
  int p = start;
  for (; p + 4 <= end; p += 4) {
    const int s0 = psrc[p + 0], s1 = psrc[p + 1];
    const int s2 = psrc[p + 2], s3 = psrc[p + 3];
    const float e0 = __expf(plg[(long)(p + 0) * 8 + h] - mh);
    const float e1 = __expf(plg[(long)(p + 1) * 8 + h] - mh);
    const float e2 = __expf(plg[(long)(p + 2) * 8 + h] - mh);
    const float e3 = __expf(plg[(long)(p + 3) * 8 + h] - mh);
    const unsigned v0 = *(const unsigned*)&xh[(long)s0 * 128 + co];
    const unsigned v1 = *(const unsigned*)&xh[(long)s1 * 128 + co];
    const unsigned v2 = *(const unsigned*)&xh[(long)s2 * 128 + co];
    const unsigned v3 = *(const unsigned*)&xh[(long)s3 * 128 + co];
    a0.x = fmaf(bflo(v0), e0, a0.x); a0.y = fmaf(bfhi(v0), e0, a0.y);
    a1.x = fmaf(bflo(v1), e1, a1.x); a1.y = fmaf(bfhi(v1), e1, a1.y);
    a2.x = fmaf(bflo(v2), e2, a2.x); a2.y = fmaf(bfhi(v2), e2, a2.y);
    a3.x = fmaf(bflo(v3), e3, a3.x); a3.y = fmaf(bfhi(v3), e3, a3.y);
  }
  for (; p < end; ++p) {
    const int s = psrc[p];
    const float e0 = __expf(plg[(long)p * 8 + h] - mh);
    const unsigned v = *(const unsigned*)&xh[(long)s * 128 + co];
    a0.x = fmaf(bflo(v), e0, a0.x);
    a0.y = fmaf(bfhi(v), e0, a0.y);
  }
  const float ax = ((a0.x + a1.x) + (a2.x + a3.x)) * rs;
  const float ay = ((a0.y + a1.y) + (a2.y + a3.y)) * rs;

  float2 o = *(float2*)&outp[(long)d * 128 + co];
  o.x += (ax > 0.f) ? ax : expm1f(ax);
  o.y += (ay > 0.f) ? ay : expm1f(ay);
  *(float2*)&outp[(long)d * 128 + co] = o;
}

extern "C" void kernel_launch(void* const* d_in, const int* in_sizes, int n_in,
                              void* d_out, int out_size, void* d_ws, size_t ws_size,
                              hipStream_t stream) {
  const float* feat = (const float*)d_in[0];
  const int*   eidx = (const int*)d_in[1];
  const float* ew   = (const float*)d_in[2];
  const float* Wlin = (const float*)d_in[3];
  const float* attl = (const float*)d_in[4];
  const float* attr = (const float*)d_in[5];
  const float* Wres = (const float*)d_in[6];
  float* outp = (float*)d_out;

  float* ws = (float*)d_ws;
  unsigned short* xh = (unsigned short*)ws;
  float* al   = ws + 5120000;
  float* ar   = ws + 5440000;
  float* plg  = ws + 5760000;
  int*   psrc = (int*)(ws + 10880000);
  int*   rowL = (int*)(ws + 11520000);
  int*   cnt  = (int*)(ws + 11700000);
  int*   cur  = (int*)(ws + 11740000);   // adjacent to cnt: one memset
  int*   bsum = (int*)(ws + 11800000);
  int*   bpre = (int*)(ws + 11810000);

  const int* src = eidx;
  const int* dst = eidx + N_EDGES;

  hipMemsetAsync(cnt, 0, (size_t)2 * N_NODES * 4, stream);  // cnt + cur

  dim3 ggrid(NB_GEMM, 3);  // y=0 lin, y=1 res, y=2 histogram
  k_gemm<<<ggrid, 256, 0, stream>>>(feat, Wlin, Wres, attl, attr, xh, al, ar,
                                    outp, dst, cnt);
  k_scan_local<<<NB_SCAN, 256, 0, stream>>>(cnt, rowL, bsum);
  k_scan_bsum<<<1, 256, 0, stream>>>(bsum, bpre);
  k_fill_logit<<<(N_EDGES + 255) / 256, 256, 0, stream>>>(src, dst, ew, al, ar,
                                                          rowL, bpre, cur, plg, psrc);
  k_node_agg<<<N_NODES / 4, 256, 0, stream>>>(rowL, bpre, psrc, plg, xh, outp);
}